// Round 11
// baseline (275.506 us; speedup 1.0000x reference)
//
#include <hip/hip_runtime.h>
#include <stdint.h>

#define BATCH 256
#define NNODE 512
#define INP   57
#define HIDD  512
#define OUTD  57

typedef int i32x4 __attribute__((ext_vector_type(4)));

// global -> LDS direct DMA, 16B/lane. LDS dest = wave-uniform base + lane*16.
__device__ __forceinline__ void gload_lds16(const void* g, void* l){
  __builtin_amdgcn_global_load_lds(
      (const __attribute__((address_space(1))) unsigned int*)g,
      (__attribute__((address_space(3))) unsigned int*)l, 16, 0, 0);
}

// Pre-pack B (i8, scale s1/127, s1 = 1/sqrt(569)) in MFMA fragment order.
// kt 0..7: Wh rows k=kt*64..+63. kt 8: K-extension = [Wx rows 0..56; b_ih; zeros].
// Fragment id = kt*32 + ntile; within: lane holds B[ksub=(lane>>4)*16+j][n=nt*16+(lane&15)].
__global__ void pack_wq(const float* __restrict__ W_ih, const float* __restrict__ b_ih,
                        signed char* __restrict__ Wq){
  int idx = blockIdx.x * 256 + threadIdx.x;      // 0..294911
  int j    =  idx        & 15;
  int lane = (idx >> 4)  & 63;
  int nt   = (idx >> 10) & 31;
  int kt   =  idx >> 15;                         // 0..8
  int n    = nt * 16 + (lane & 15);
  int ksub = (lane >> 4) * 16 + j;               // 0..63
  const float scale = 127.0f * sqrtf((float)(INP + HIDD));
  float wv;
  if (kt < 8)            wv = W_ih[(size_t)(INP + kt * 64 + ksub) * HIDD + n];
  else if (ksub < INP)   wv = W_ih[(size_t)ksub * HIDD + n];
  else if (ksub == INP)  wv = b_ih[n];
  else                   wv = 0.0f;
  float q = rintf(wv * scale);
  q = fminf(127.0f, fmaxf(-127.0f, q));
  Wq[idx] = (signed char)q;
}

// One level-chunk (<= NMT*16 rows): DMA-gather child rows into fragment slabs
// (wave w stages kt=w for all m-tiles), build one-hot Xp extension slabs, MFMA
// (acc = A_l*B + A_r*B + ext*Bext), tanh, i8 scatter.
// Al slab id = kt*4 + mt; ext slabs at id 32+mt. li_s/ri_s hold PRE-RESOLVED
// byte offsets ((child<0?512:child)*512); ordoff_s holds node*512.
template<int NMT>
__device__ __forceinline__ void chunk_body(
    int m0, int Mcur, int w, int lane, int m16, int quad,
    signed char* __restrict__ Al, signed char* __restrict__ Ar,
    const int* ord_s, const int* li_s, const int* ri_s, const int* val_s,
    const int* ordoff_s,
    const i32x4 (&Bv)[9][4],
    signed char* Hb)
{
  // ---- gather: wave w DMAs kt=w slabs for mt=0..NMT-1, both sides ----
  {
    const int kt = w;                            // 0..7
    const int koff = kt * 64 + quad * 16;
    #pragma unroll
    for (int mt = 0; mt < NMT; ++mt) {
      const int row  = mt * 16 + m16;
      const int node = (row < Mcur) ? ord_s[m0 + row] : -1;
      const int loff = (node >= 0) ? li_s[node] : NNODE * HIDD;
      gload_lds16(Hb + (size_t)(loff + koff), Al + (kt * 4 + mt) * 1024);
      const int roff = (node >= 0) ? ri_s[node] : NNODE * HIDD;
      gload_lds16(Hb + (size_t)(roff + koff), Ar + (kt * 4 + mt) * 1024);
    }
    // one-hot extension slab(s): A_ext[row][ksub] = 127 at ksub==val and ksub==INP
    if (w < NMT) {
      const int erow  = w * 16 + m16;
      const int enode = (erow < Mcur) ? ord_s[m0 + erow] : -1;
      const int v     = (enode >= 0) ? val_s[enode] : -1;
      signed char bytes[16];
      #pragma unroll
      for (int j = 0; j < 16; ++j) {
        const int ks = quad * 16 + j;
        bytes[j] = (enode >= 0 && (ks == v || ks == INP)) ? (signed char)127 : (signed char)0;
      }
      *(i32x4*)(Al + (32 + w) * 1024 + lane * 16) = *(const i32x4*)bytes;
    }
  }
  __syncthreads();                               // drains vmcnt+lgkm -> slabs resident

  // ---- MFMA: wave w owns n-tiles 4w..4w+3 ----
  i32x4 acc[NMT][4];
  #pragma unroll
  for (int mt = 0; mt < NMT; ++mt)
    #pragma unroll
    for (int nt = 0; nt < 4; ++nt)
      acc[mt][nt] = (i32x4){0, 0, 0, 0};

  #pragma unroll
  for (int kt = 0; kt < 8; ++kt) {
    #pragma unroll
    for (int mt = 0; mt < NMT; ++mt) {
      i32x4 al = *(const i32x4*)(Al + (kt * 4 + mt) * 1024 + lane * 16);
      #pragma unroll
      for (int nt = 0; nt < 4; ++nt)
        acc[mt][nt] = __builtin_amdgcn_mfma_i32_16x16x64_i8(al, Bv[kt][nt], acc[mt][nt], 0, 0, 0);
      i32x4 ar = *(const i32x4*)(Ar + (kt * 4 + mt) * 1024 + lane * 16);
      #pragma unroll
      for (int nt = 0; nt < 4; ++nt)
        acc[mt][nt] = __builtin_amdgcn_mfma_i32_16x16x64_i8(ar, Bv[kt][nt], acc[mt][nt], 0, 0, 0);
    }
  }
  #pragma unroll
  for (int mt = 0; mt < NMT; ++mt) {             // kt=8: one-hot Xp + bias
    i32x4 ax = *(const i32x4*)(Al + (32 + mt) * 1024 + lane * 16);
    #pragma unroll
    for (int nt = 0; nt < 4; ++nt)
      acc[mt][nt] = __builtin_amdgcn_mfma_i32_16x16x64_i8(ax, Bv[8][nt], acc[mt][nt], 0, 0, 0);
  }

  // ---- epilogue: h = tanh(acc*SCL), store i8. C/D: col=lane&15, row=quad*4+rg ----
  // Row-outer: one ordoff read + one address per ROW; nt via +16 offsets.
  const float SCL2 = 2.0f / (16129.0f * sqrtf((float)(INP + HIDD)));  // 2*s1/127^2
  #pragma unroll
  for (int mt = 0; mt < NMT; ++mt) {
    #pragma unroll
    for (int rg = 0; rg < 4; ++rg) {
      const int rowc = mt * 16 + quad * 4 + rg;
      if (rowc < Mcur) {
        signed char* hp = Hb + (size_t)ordoff_s[m0 + rowc] + (w * 64 + m16);
        #pragma unroll
        for (int nt = 0; nt < 4; ++nt) {
          const float e  = __expf((float)acc[mt][nt][rg] * SCL2);
          const float tq = 127.0f - __fdividef(254.0f, e + 1.0f);   // 127*tanh
          hp[nt * 16] = (signed char)__float2int_rn(tq);
        }
      }
    }
  }
  __syncthreads();
}

// One block (512 threads = 8 waves = 2 waves/SIMD) per batch row.
// 2 waves/SIMD -> 256-reg/wave budget; Bv[9][4] = 144 regs + acc[4][4] = 64.
__global__ __launch_bounds__(512, 2) void tree_rnn(
    const int* __restrict__ left, const int* __restrict__ right,
    const int* __restrict__ values,
    const float* __restrict__ W_ih, const float* __restrict__ b_ih,
    const float* __restrict__ W_o,  const float* __restrict__ b_o,
    const signed char* __restrict__ Wq,
    signed char* __restrict__ Hbuf, float* __restrict__ out)
{
  __shared__ __align__(16) signed char Al_s[36 * 1024];   // 8 kt x 4 mt + 4 ext slabs
  __shared__ __align__(16) signed char Ar_s[32 * 1024];   // 8 kt x 4 mt slabs
  __shared__ int li_s[NNODE], ri_s[NNODE], val_s[NNODE];
  __shared__ int lvl_s[NNODE], ord_s[NNODE], ordoff_s[NNODE];
  __shared__ int cnt_s[NNODE], cnt2_s[NNODE];
  __shared__ int offs_s[NNODE + 1];
  __shared__ int chg_s, lmax_s;
  __shared__ float hroot_s[HIDD];
  __shared__ float red_s[OUTD][8];
  __shared__ float logit_s[64];

  const int b    = blockIdx.x;
  const int tid  = threadIdx.x;                  // 0..511, one per node in prepass
  const int lane = tid & 63;
  const int w    = tid >> 6;                     // 0..7
  signed char* Hb = Hbuf + (size_t)b * (NNODE + 1) * HIDD;

  // ---- load tree + init (ws is poisoned 0xAA: must zero sentinel row) ----
  li_s[tid]  = left  [b * NNODE + tid];
  ri_s[tid]  = right [b * NNODE + tid];
  val_s[tid] = values[b * NNODE + tid];
  lvl_s[tid] = 0; cnt_s[tid] = 0; cnt2_s[tid] = 0;
  if (tid < 128) ((unsigned int*)(Hb + (size_t)NNODE * HIDD))[tid] = 0;  // null-child row
  if (tid == 0) lmax_s = 0;
  __syncthreads();

  // ---- level fixpoint: lvl[i] = 1 + max(lvl[children]), null -> -1 ----
  for (;;) {
    if (tid == 0) chg_s = 0;
    __syncthreads();
    {
      int l = li_s[tid], r = ri_s[tid];
      int dl = (l >= 0) ? lvl_s[l] : -1;
      int dr = (r >= 0) ? lvl_s[r] : -1;
      int nl = 1 + (dl > dr ? dl : dr);
      if (nl > lvl_s[tid]) { lvl_s[tid] = nl; chg_s = 1; }   // monotone -> converges
    }
    __syncthreads();
    if (!chg_s) break;
  }

  // ---- bucket nodes by level (counting sort in LDS) ----
  const int myl = lvl_s[tid];
  {
    int ml = myl;
    #pragma unroll
    for (int m = 1; m < 64; m <<= 1) ml = max(ml, __shfl_xor(ml, m, 64));
    if (lane == 0) atomicMax(&lmax_s, ml);
    atomicAdd(&cnt_s[myl], 1);
  }
  __syncthreads();
  const int Lmax = lmax_s;
  if (tid == 0) {
    int acc = 0;
    for (int L = 0; L <= Lmax; ++L) { offs_s[L] = acc; acc += cnt_s[L]; }
    offs_s[Lmax + 1] = acc;                      // == 512
  }
  __syncthreads();
  {
    int pos = offs_s[myl] + atomicAdd(&cnt2_s[myl], 1);
    ord_s[pos] = tid;
    ordoff_s[pos] = tid * HIDD;                  // node byte-offset for epilogue
  }
  __syncthreads();
  // resolve child ids -> byte offsets (fixpoint no longer needs raw ids)
  {
    int l = li_s[tid], r = ri_s[tid];
    li_s[tid] = (l < 0 ? NNODE : l) * HIDD;
    ri_s[tid] = (r < 0 ? NNODE : r) * HIDD;
  }
  __syncthreads();

  const int m16  = lane & 15;
  const int quad = lane >> 4;

  // ---- this wave's B slice, loaded once: 9 kt x 4 n-tiles = 144 regs/lane ----
  i32x4 Bv[9][4];
  #pragma unroll
  for (int kt = 0; kt < 9; ++kt)
    #pragma unroll
    for (int nt = 0; nt < 4; ++nt)
      Bv[kt][nt] = *(const i32x4*)(Wq + ((size_t)(kt * 32 + 4 * w + nt) * 64 + lane) * 16);

  // ---- level loop: per level, GEMM (Mcur x 512) @ Wh(512x512), tanh, scatter ----
  for (int L = 0; L <= Lmax; ++L) {
    const int start = offs_s[L], end = offs_s[L + 1];
    int m0 = start;
    while (m0 < end) {
      const int rem = end - m0;
      if (rem > 32) {
        chunk_body<4>(m0, min(64, rem), w, lane, m16, quad, Al_s, Ar_s,
                      ord_s, li_s, ri_s, val_s, ordoff_s, Bv, Hb);
        m0 += 64;
      } else if (rem > 16) {
        chunk_body<2>(m0, rem, w, lane, m16, quad, Al_s, Ar_s,
                      ord_s, li_s, ri_s, val_s, ordoff_s, Bv, Hb);
        m0 += 32;
      } else {
        chunk_body<1>(m0, rem, w, lane, m16, quad, Al_s, Ar_s,
                      ord_s, li_s, ri_s, val_s, ordoff_s, Bv, Hb);
        m0 += 16;
      }
    }
  }

  // ---- logits + log_softmax for this batch row ----
  hroot_s[tid] = (float)Hb[(size_t)(NNODE - 1) * HIDD + tid] * (1.0f / 127.0f);
  __syncthreads();
  {
    const int j = tid >> 3, part = tid & 7;      // 8 threads per output
    if (j < OUTD) {
      float p = 0.f;
      const int k0 = part * 64;
      for (int k = k0; k < k0 + 64; ++k)
        p += hroot_s[k] * W_o[(size_t)k * OUTD + j];
      red_s[j][part] = p;
    }
  }
  __syncthreads();
  if (tid < OUTD) {
    float s = b_o[tid];
    #pragma unroll
    for (int p = 0; p < 8; ++p) s += red_s[tid][p];
    logit_s[tid] = s;
  }
  __syncthreads();
  if (w == 0) {
    float x = (lane < OUTD) ? logit_s[lane] : -1e30f;
    float mx = x;
    #pragma unroll
    for (int m = 1; m < 64; m <<= 1) mx = fmaxf(mx, __shfl_xor(mx, m, 64));
    float ex = (lane < OUTD) ? __expf(x - mx) : 0.f;
    float sm = ex;
    #pragma unroll
    for (int m = 1; m < 64; m <<= 1) sm += __shfl_xor(sm, m, 64);
    float ls = logf(sm);
    if (lane < OUTD) out[b * OUTD + lane] = x - mx - ls;
  }
}

extern "C" void kernel_launch(void* const* d_in, const int* in_sizes, int n_in,
                              void* d_out, int out_size, void* d_ws, size_t ws_size,
                              hipStream_t stream) {
  const int*   left   = (const int*)  d_in[0];
  const int*   right  = (const int*)  d_in[1];
  const int*   values = (const int*)  d_in[2];
  const float* W_ih   = (const float*)d_in[3];
  const float* b_ih   = (const float*)d_in[4];
  const float* W_o    = (const float*)d_in[5];
  const float* b_o    = (const float*)d_in[6];
  float* out = (float*)d_out;

  // workspace: [0, 512KB) packed B i8 (288KB used); then H: 256 x 513 x 512 i8 (~67 MB)
  signed char* Wq   = (signed char*)d_ws;
  signed char* Hbuf = (signed char*)((char*)d_ws + 512 * 1024);

  pack_wq<<<1152, 256, 0, stream>>>(W_ih, b_ih, Wq);
  tree_rnn<<<BATCH, 512, 0, stream>>>(left, right, values, W_ih, b_ih, W_o, b_o,
                                      Wq, Hbuf, out);
}

// Round 12
// 209.886 us; speedup vs baseline: 1.3126x; 1.3126x over previous
//
#include <hip/hip_runtime.h>
#include <stdint.h>

#define BATCH 256
#define NNODE 512
#define INP   57
#define HIDD  512
#define OUTD  57

typedef int i32x4 __attribute__((ext_vector_type(4)));

// global -> LDS direct DMA, 16B/lane. LDS dest = wave-uniform base + lane*16.
__device__ __forceinline__ void gload_lds16(const void* g, void* l){
  __builtin_amdgcn_global_load_lds(
      (const __attribute__((address_space(1))) unsigned int*)g,
      (__attribute__((address_space(3))) unsigned int*)l, 16, 0, 0);
}

// Pre-pack B (i8, scale s1/127, s1 = 1/sqrt(569)) in MFMA fragment order.
// kt 0..7: Wh rows k=kt*64..+63. kt 8: K-extension = [Wx rows 0..56; b_ih; zeros].
// Fragment id = kt*32 + ntile; within: lane holds B[ksub=(lane>>4)*16+j][n=nt*16+(lane&15)].
__global__ void pack_wq(const float* __restrict__ W_ih, const float* __restrict__ b_ih,
                        signed char* __restrict__ Wq){
  int idx = blockIdx.x * 256 + threadIdx.x;      // 0..294911
  int j    =  idx        & 15;
  int lane = (idx >> 4)  & 63;
  int nt   = (idx >> 10) & 31;
  int kt   =  idx >> 15;                         // 0..8
  int n    = nt * 16 + (lane & 15);
  int ksub = (lane >> 4) * 16 + j;               // 0..63
  const float scale = 127.0f * sqrtf((float)(INP + HIDD));
  float wv;
  if (kt < 8)            wv = W_ih[(size_t)(INP + kt * 64 + ksub) * HIDD + n];
  else if (ksub < INP)   wv = W_ih[(size_t)ksub * HIDD + n];
  else if (ksub == INP)  wv = b_ih[n];
  else                   wv = 0.0f;
  float q = rintf(wv * scale);
  q = fminf(127.0f, fmaxf(-127.0f, q));
  Wq[idx] = (signed char)q;
}

// Issue the gather DMAs for one chunk (always both m-tiles; dead rows pull the
// sentinel zero row) + build the one-hot Xp extension slabs. No waits here —
// the caller's next __syncthreads() drains vmcnt/lgkmcnt.
__device__ __forceinline__ void issue_gather(
    int m0, int Mcur, int w, int lane, int m16, int quad,
    signed char* __restrict__ Ab, signed char* __restrict__ Rb,
    const int* ord_s, const int* li_s, const int* ri_s, const int* val_s,
    signed char* Hb)
{
  const int kt   = w;                            // 0..7
  const int koff = kt * 64 + quad * 16;
  #pragma unroll
  for (int mt = 0; mt < 2; ++mt) {
    const int row  = mt * 16 + m16;
    const int node = (row < Mcur) ? ord_s[m0 + row] : -1;
    const int loff = (node >= 0) ? li_s[node] : NNODE * HIDD;
    gload_lds16(Hb + (size_t)(loff + koff), Ab + (kt * 2 + mt) * 1024);
    const int roff = (node >= 0) ? ri_s[node] : NNODE * HIDD;
    gload_lds16(Hb + (size_t)(roff + koff), Rb + (kt * 2 + mt) * 1024);
  }
  if (w < 2) {                                   // ext slabs (one per m-tile)
    const int erow  = w * 16 + m16;
    const int enode = (erow < Mcur) ? ord_s[m0 + erow] : -1;
    const int v     = (enode >= 0) ? val_s[enode] : -1;
    signed char bytes[16];
    #pragma unroll
    for (int j = 0; j < 16; ++j) {
      const int ks = quad * 16 + j;
      bytes[j] = (enode >= 0 && (ks == v || ks == INP)) ? (signed char)127 : (signed char)0;
    }
    *(i32x4*)(Ab + (16 + w) * 1024 + lane * 16) = *(const i32x4*)bytes;
  }
}

// MFMA + tanh epilogue for one chunk (slabs already resident).
template<int NMT>
__device__ __forceinline__ void compute_chunk(
    int m0, int Mcur, int w, int lane, int m16, int quad,
    const signed char* __restrict__ Ab, const signed char* __restrict__ Rb,
    const int* ordoff_s, const i32x4 (&Bv)[9][4], signed char* Hb)
{
  i32x4 acc[NMT][4];
  #pragma unroll
  for (int mt = 0; mt < NMT; ++mt)
    #pragma unroll
    for (int nt = 0; nt < 4; ++nt)
      acc[mt][nt] = (i32x4){0, 0, 0, 0};

  #pragma unroll
  for (int kt = 0; kt < 8; ++kt) {
    #pragma unroll
    for (int mt = 0; mt < NMT; ++mt) {
      i32x4 al = *(const i32x4*)(Ab + (kt * 2 + mt) * 1024 + lane * 16);
      #pragma unroll
      for (int nt = 0; nt < 4; ++nt)
        acc[mt][nt] = __builtin_amdgcn_mfma_i32_16x16x64_i8(al, Bv[kt][nt], acc[mt][nt], 0, 0, 0);
      i32x4 ar = *(const i32x4*)(Rb + (kt * 2 + mt) * 1024 + lane * 16);
      #pragma unroll
      for (int nt = 0; nt < 4; ++nt)
        acc[mt][nt] = __builtin_amdgcn_mfma_i32_16x16x64_i8(ar, Bv[kt][nt], acc[mt][nt], 0, 0, 0);
    }
  }
  #pragma unroll
  for (int mt = 0; mt < NMT; ++mt) {             // kt=8: one-hot Xp + bias
    i32x4 ax = *(const i32x4*)(Ab + (16 + mt) * 1024 + lane * 16);
    #pragma unroll
    for (int nt = 0; nt < 4; ++nt)
      acc[mt][nt] = __builtin_amdgcn_mfma_i32_16x16x64_i8(ax, Bv[8][nt], acc[mt][nt], 0, 0, 0);
  }

  // epilogue: 127*tanh(acc*s1/127^2) = 127 - 254/(exp2(acc*SCLE)+1),
  // SCLE = 2*log2(e)*s1/127^2 (constant-folded). 6 VALU/element.
  const float SCLE = 2.8853900817779268f / (16129.0f * sqrtf((float)(INP + HIDD)));
  #pragma unroll
  for (int mt = 0; mt < NMT; ++mt) {
    #pragma unroll
    for (int rg = 0; rg < 4; ++rg) {
      const int rowc = mt * 16 + quad * 4 + rg;
      if (rowc < Mcur) {
        signed char* hp = Hb + (size_t)ordoff_s[m0 + rowc] + (w * 64 + m16);
        #pragma unroll
        for (int nt = 0; nt < 4; ++nt) {
          const float x  = (float)acc[mt][nt][rg] * SCLE;
          const float e  = __builtin_amdgcn_exp2f(x);
          const float r  = __builtin_amdgcn_rcpf(e + 1.0f);
          const float tq = fmaf(-254.0f, r, 127.0f);
          hp[nt * 16] = (signed char)__float2int_rn(tq);
        }
      }
    }
  }
}

// One block (512 threads = 8 waves = 2 waves/SIMD) per batch row.
// Level-scheduled tree RNN; within-level software pipeline with double-buffered
// A slabs (gather DMA for chunk c+1 issued before compute of chunk c);
// one barrier per chunk steady-state.
__global__ __launch_bounds__(512, 2) void tree_rnn(
    const int* __restrict__ left, const int* __restrict__ right,
    const int* __restrict__ values,
    const float* __restrict__ W_ih, const float* __restrict__ b_ih,
    const float* __restrict__ W_o,  const float* __restrict__ b_o,
    const signed char* __restrict__ Wq,
    signed char* __restrict__ Hbuf, float* __restrict__ out)
{
  __shared__ __align__(16) signed char Abuf[2][18 * 1024]; // 8kt x 2mt + 2 ext slabs
  __shared__ __align__(16) signed char Rbuf[2][16 * 1024]; // 8kt x 2mt slabs
  __shared__ int li_s[NNODE], ri_s[NNODE], val_s[NNODE];
  __shared__ int lvl_s[NNODE], ord_s[NNODE], ordoff_s[NNODE];
  __shared__ int cnt_s[NNODE], cnt2_s[NNODE];
  __shared__ int offs_s[NNODE + 1];
  __shared__ int chg_s, lmax_s;
  __shared__ float hroot_s[HIDD];
  __shared__ float red_s[OUTD][8];
  __shared__ float logit_s[64];

  const int b    = blockIdx.x;
  const int tid  = threadIdx.x;                  // 0..511, one per node in prepass
  const int lane = tid & 63;
  const int w    = tid >> 6;                     // 0..7
  signed char* Hb = Hbuf + (size_t)b * (NNODE + 1) * HIDD;

  // ---- load tree + init (ws is poisoned 0xAA: must zero sentinel row) ----
  li_s[tid]  = left  [b * NNODE + tid];
  ri_s[tid]  = right [b * NNODE + tid];
  val_s[tid] = values[b * NNODE + tid];
  lvl_s[tid] = 0; cnt_s[tid] = 0; cnt2_s[tid] = 0;
  if (tid < 128) ((unsigned int*)(Hb + (size_t)NNODE * HIDD))[tid] = 0;  // null-child row
  if (tid == 0) lmax_s = 0;
  __syncthreads();

  // ---- level fixpoint: lvl[i] = 1 + max(lvl[children]), null -> -1 ----
  for (;;) {
    if (tid == 0) chg_s = 0;
    __syncthreads();
    {
      int l = li_s[tid], r = ri_s[tid];
      int dl = (l >= 0) ? lvl_s[l] : -1;
      int dr = (r >= 0) ? lvl_s[r] : -1;
      int nl = 1 + (dl > dr ? dl : dr);
      if (nl > lvl_s[tid]) { lvl_s[tid] = nl; chg_s = 1; }   // monotone -> converges
    }
    __syncthreads();
    if (!chg_s) break;
  }

  // ---- bucket nodes by level (counting sort in LDS) ----
  const int myl = lvl_s[tid];
  {
    int ml = myl;
    #pragma unroll
    for (int m = 1; m < 64; m <<= 1) ml = max(ml, __shfl_xor(ml, m, 64));
    if (lane == 0) atomicMax(&lmax_s, ml);
    atomicAdd(&cnt_s[myl], 1);
  }
  __syncthreads();
  const int Lmax = lmax_s;
  if (tid == 0) {
    int acc = 0;
    for (int L = 0; L <= Lmax; ++L) { offs_s[L] = acc; acc += cnt_s[L]; }
    offs_s[Lmax + 1] = acc;                      // == 512
  }
  __syncthreads();
  {
    int pos = offs_s[myl] + atomicAdd(&cnt2_s[myl], 1);
    ord_s[pos] = tid;
    ordoff_s[pos] = tid * HIDD;                  // node byte-offset for epilogue
  }
  __syncthreads();
  // resolve child ids -> byte offsets (fixpoint no longer needs raw ids)
  {
    int l = li_s[tid], r = ri_s[tid];
    li_s[tid] = (l < 0 ? NNODE : l) * HIDD;
    ri_s[tid] = (r < 0 ? NNODE : r) * HIDD;
  }

  const int m16  = lane & 15;
  const int quad = lane >> 4;

  // ---- this wave's B slice, loaded once: 9 kt x 4 n-tiles = 144 regs/lane ----
  i32x4 Bv[9][4];
  #pragma unroll
  for (int kt = 0; kt < 9; ++kt)
    #pragma unroll
    for (int nt = 0; nt < 4; ++nt)
      Bv[kt][nt] = *(const i32x4*)(Wq + ((size_t)(kt * 32 + 4 * w + nt) * 64 + lane) * 16);

  // ---- level loop: pipelined chunks of 32 rows ----
  for (int L = 0; L <= Lmax; ++L) {
    const int start = offs_s[L], end = offs_s[L + 1];
    const int nch = (end - start + 31) >> 5;
    __syncthreads();                             // prev-level H stores + li_s rewrite visible
    issue_gather(start, min(32, end - start), w, lane, m16, quad,
                 Abuf[0], Rbuf[0], ord_s, li_s, ri_s, val_s, Hb);
    for (int c = 0; c < nch; ++c) {
      __syncthreads();                           // gather c complete (vmcnt+lgkm drained)
      const int m0 = start + c * 32;
      const int Mc = min(32, end - m0);
      if (c + 1 < nch) {                         // prefetch next chunk (same level: safe)
        const int m1 = m0 + 32;
        issue_gather(m1, min(32, end - m1), w, lane, m16, quad,
                     Abuf[(c + 1) & 1], Rbuf[(c + 1) & 1],
                     ord_s, li_s, ri_s, val_s, Hb);
      }
      const signed char* Ab = Abuf[c & 1];
      const signed char* Rb = Rbuf[c & 1];
      if (Mc > 16)
        compute_chunk<2>(m0, Mc, w, lane, m16, quad, Ab, Rb, ordoff_s, Bv, Hb);
      else
        compute_chunk<1>(m0, Mc, w, lane, m16, quad, Ab, Rb, ordoff_s, Bv, Hb);
    }
  }
  __syncthreads();                               // final level's H stores visible

  // ---- logits + log_softmax for this batch row ----
  hroot_s[tid] = (float)Hb[(size_t)(NNODE - 1) * HIDD + tid] * (1.0f / 127.0f);
  __syncthreads();
  {
    const int j = tid >> 3, part = tid & 7;      // 8 threads per output
    if (j < OUTD) {
      float p = 0.f;
      const int k0 = part * 64;
      for (int k = k0; k < k0 + 64; ++k)
        p += hroot_s[k] * W_o[(size_t)k * OUTD + j];
      red_s[j][part] = p;
    }
  }
  __syncthreads();
  if (tid < OUTD) {
    float s = b_o[tid];
    #pragma unroll
    for (int p = 0; p < 8; ++p) s += red_s[tid][p];
    logit_s[tid] = s;
  }
  __syncthreads();
  if (w == 0) {
    float x = (lane < OUTD) ? logit_s[lane] : -1e30f;
    float mx = x;
    #pragma unroll
    for (int m = 1; m < 64; m <<= 1) mx = fmaxf(mx, __shfl_xor(mx, m, 64));
    float ex = (lane < OUTD) ? __expf(x - mx) : 0.f;
    float sm = ex;
    #pragma unroll
    for (int m = 1; m < 64; m <<= 1) sm += __shfl_xor(sm, m, 64);
    float ls = logf(sm);
    if (lane < OUTD) out[b * OUTD + lane] = x - mx - ls;
  }
}

extern "C" void kernel_launch(void* const* d_in, const int* in_sizes, int n_in,
                              void* d_out, int out_size, void* d_ws, size_t ws_size,
                              hipStream_t stream) {
  const int*   left   = (const int*)  d_in[0];
  const int*   right  = (const int*)  d_in[1];
  const int*   values = (const int*)  d_in[2];
  const float* W_ih   = (const float*)d_in[3];
  const float* b_ih   = (const float*)d_in[4];
  const float* W_o    = (const float*)d_in[5];
  const float* b_o    = (const float*)d_in[6];
  float* out = (float*)d_out;

  // workspace: [0, 512KB) packed B i8 (288KB used); then H: 256 x 513 x 512 i8 (~67 MB)
  signed char* Wq   = (signed char*)d_ws;
  signed char* Hbuf = (signed char*)((char*)d_ws + 512 * 1024);

  pack_wq<<<1152, 256, 0, stream>>>(W_ih, b_ih, Wq);
  tree_rnn<<<BATCH, 512, 0, stream>>>(left, right, values, W_ih, b_ih, W_o, b_o,
                                      Wq, Hbuf, out);
}